// Round 3
// baseline (147.050 us; speedup 1.0000x reference)
//
#include <hip/hip_runtime.h>

#define NCH 32          // channels
#define GROUPS 8        // float4 groups per row (32 / 4)
#define KVOL 27         // 3^3 kernel offsets
#define LG 100          // grid side
#define LP 102          // padded side (1-cell zero ring)
#define RGN 5           // region side per block
#define NRGN 20         // LG / RGN
#define NREGIONS (NRGN * NRGN * NRGN)   // 8000
#define BSIDE 7         // RGN + 2
#define BVOL 343        // brick cells
#define CELLS 125       // RGN^3
#define FSTR 9          // kw float4 stride (row k at byte k*144)
#define LSTR 28         // uint taps per row (112B, 16B-aligned)

// ---- Kernel 1: dense presence map (NO pre-zeroing needed) -------------------
// dense[flatp] = row+1; consumers back-validate via coords, so stale/garbage
// workspace contents are harmless.
__global__ void build_dense(const int* __restrict__ coords,
                            int* __restrict__ dense, int N) {
    int i = blockIdx.x * blockDim.x + threadIdx.x;
    if (i >= N) return;
    int x = coords[3 * i + 0];
    int y = coords[3 * i + 1];
    int z = coords[3 * i + 2];
    dense[((size_t)(x + 1) * LP + (y + 1)) * LP + (z + 1)] = i + 1;
}

// ---- Kernel 2: region gather ------------------------------------------------
// Brick load back-validates candidates (no memset). Tap lists are uint
// (row<<13 | k*144): direct global row + pre-scaled kw byte offset -> no
// indirection in the inner loop. Fill is ballot-based (no LDS atomics, dword
// writes). Rows counting-sorted by tap count for octet load balance.
__global__ __launch_bounds__(256) void gather_conv_region(
        const int* __restrict__ coords,
        const int* __restrict__ dense,
        const float4* __restrict__ in_feats4,
        const float4* __restrict__ kernel4,
        float4* __restrict__ out4, int N) {
    __shared__ float4 kw[(KVOL + 1) * FSTR];        // 4032 B (row 27 = zeros)
    __shared__ int brick[BVOL];                     // validated row+1 (0=empty)
    __shared__ int qcell[CELLS];                    // queue -> brick cell
    __shared__ int fillA[CELLS];                    // (rank<<8) | padded count
    __shared__ int smapq[CELLS];                    // sorted -> (q<<8)|cnt
    __shared__ int smapr[CELLS];                    // sorted -> output row
    __shared__ int hist[7];
    __shared__ unsigned int list[CELLS * LSTR];     // 14000 B
    __shared__ int nint;

    int tid = threadIdx.x;
    int g   = tid & 7;

    if (tid == 0) nint = 0;
    if (tid < 7) hist[tid] = 0;
    if (tid < (KVOL + 1) * GROUPS) {
        int kr = tid >> 3;
        kw[kr * FSTR + g] = (kr < KVOL) ? kernel4[kr * GROUPS + g]
                                        : make_float4(0.f, 0.f, 0.f, 0.f);
    }

    // XCD slab swizzle (8000 % 8 == 0 -> bijective)
    int b = blockIdx.x;
    int r = (b & 7) * (NREGIONS >> 3) + (b >> 3);
    int bx = r / (NRGN * NRGN);
    int by = (r / NRGN) % NRGN;
    int bz = r % NRGN;
    int ox = bx * RGN, oy = by * RGN, oz = bz * RGN;

    // Brick load with back-validation: candidate v is real iff coords[v-1]
    // equals this cell. Stale/poison entries can't pass; passing entries are
    // correct by row-uniqueness. Interior occupied cells enter the queue.
    for (int i = tid; i < BVOL; i += 256) {
        int lx = i / 49, ly = (i / 7) % 7, lz = i % 7;
        int gx = ox + lx - 1, gy = oy + ly - 1, gz = oz + lz - 1;
        int v = dense[((size_t)(gx + 1) * LP + (gy + 1)) * LP + (gz + 1)];
        int row = v - 1;
        int val = 0;
        if ((unsigned)row < (unsigned)N) {
            const int* c = coords + (size_t)row * 3;
            if (c[0] == gx && c[1] == gy && c[2] == gz) val = v;
        }
        brick[i] = val;
        if (val && (unsigned)(lx - 1) < RGN && (unsigned)(ly - 1) < RGN &&
            (unsigned)(lz - 1) < RGN) {
            int p = atomicAdd(&nint, 1);
            qcell[p] = i;
        }
    }
    __syncthreads();

    int n = nint;

    // Fill: one octet per queued cell; lanes cover k = l, l+8, l+16, l+24.
    // Positions via ballot-prefix within the octet -> no atomics, dword writes.
    int oct = tid >> 3, l = tid & 7;
    int rounds = (n + 31) >> 5;                     // block-uniform
    for (int rd = 0; rd < rounds; ++rd) {
        int q = (rd << 5) + oct;
        bool valid = q < n;
        int cell = valid ? qcell[q] : 0;
        int cnt = 0;
        unsigned base = (unsigned)q * LSTR;
        #pragma unroll
        for (int s = 0; s < 4; ++s) {
            int k = l + (s << 3);
            int nb = 0;
            if (valid && k < KVOL) {
                int off = (k / 9) * 49 + ((k / 3) % 3) * 7 + (k % 3) - 57;
                nb = brick[cell + off];
            }
            unsigned long long bal = __ballot(nb > 0);
            int byte = (int)((bal >> ((oct & 7) << 3)) & 0xFF);
            if (nb > 0) {
                int pos = cnt + __popc(byte & ((1 << l) - 1));
                list[base + pos] =
                    ((unsigned)(nb - 1) << 13) | (unsigned)(k * 144);
            }
            cnt += __popc(byte);
        }
        if (valid && l == 0) {
            int j = cnt;                             // >=1 (center tap)
            unsigned dummy = ((unsigned)(brick[cell] - 1) << 13) | (27u * 144u);
            while (j & 3) list[base + (j++)] = dummy; // k=27 row: zero weights
            int bin = (j >> 2) - 1;                  // 0..6
            int h = atomicAdd(&hist[bin], 1);        // <=37 adds over 7 bins
            fillA[q] = (h << 8) | j;
        }
    }
    __syncthreads();

    // Placement: descending tap count -> octets in a wave get equal trips.
    if (tid < n) {
        int f = fillA[tid];
        int j = f & 255;
        int bin = (j >> 2) - 1;
        int pos = f >> 8;
        #pragma unroll
        for (int bb = 1; bb < 7; ++bb)
            if (bb > bin) pos += hist[bb];
        smapq[pos] = (tid << 8) | j;
        smapr[pos] = brick[qcell[tid]] - 1;
    }
    __syncthreads();

    // Gather: octet per row; one b128 list read + 4 global feat loads +
    // 4 b128 kw reads per 4 taps. kw offset comes pre-scaled in the entry.
    const char* kwb = (const char*)kw + (g << 4);
    int lr = tid >> 3;
    for (int base = 0; base < n; base += 32) {
        int lo = base + lr;
        if (lo < n) {
            int d    = smapq[lo];
            int q    = d >> 8;
            int nq   = (d & 255) >> 2;
            int orow = smapr[lo];
            const uint4* tl = (const uint4*)&list[(unsigned)q * LSTR];
            float4 acc = make_float4(0.f, 0.f, 0.f, 0.f);
            for (int jq = 0; jq < nq; ++jq) {
                uint4 L = tl[jq];
                float4 f0 = in_feats4[(size_t)(L.x >> 13) * GROUPS + g];
                float4 f1 = in_feats4[(size_t)(L.y >> 13) * GROUPS + g];
                float4 f2 = in_feats4[(size_t)(L.z >> 13) * GROUPS + g];
                float4 f3 = in_feats4[(size_t)(L.w >> 13) * GROUPS + g];
                float4 w0 = *(const float4*)(kwb + (L.x & 0x1FFFu));
                float4 w1 = *(const float4*)(kwb + (L.y & 0x1FFFu));
                float4 w2 = *(const float4*)(kwb + (L.z & 0x1FFFu));
                float4 w3 = *(const float4*)(kwb + (L.w & 0x1FFFu));
                acc.x += f0.x * w0.x; acc.y += f0.y * w0.y;
                acc.z += f0.z * w0.z; acc.w += f0.w * w0.w;
                acc.x += f1.x * w1.x; acc.y += f1.y * w1.y;
                acc.z += f1.z * w1.z; acc.w += f1.w * w1.w;
                acc.x += f2.x * w2.x; acc.y += f2.y * w2.y;
                acc.z += f2.z * w2.z; acc.w += f2.w * w2.w;
                acc.x += f3.x * w3.x; acc.y += f3.y * w3.y;
                acc.z += f3.z * w3.z; acc.w += f3.w * w3.w;
            }
            out4[(size_t)orow * GROUPS + g] = acc;
        }
    }
}

// ---- Fallback (atomic scatter) if ws is too small ---------------------------
__global__ void mink_conv_scatter(const int* __restrict__ coords,
                                  const int* __restrict__ in_idx,
                                  const int* __restrict__ out_idx,
                                  const float4* __restrict__ in_feats4,
                                  const float4* __restrict__ kernel4,
                                  float* __restrict__ out,
                                  int E) {
    __shared__ float4 kws[KVOL * GROUPS];
    for (int i = threadIdx.x; i < KVOL * GROUPS; i += blockDim.x)
        kws[i] = kernel4[i];
    __syncthreads();
    int t = blockIdx.x * blockDim.x + threadIdx.x;
    if (t >= E * GROUPS) return;
    int e = t >> 3, g = t & 7;
    int vi = in_idx[e], vo = out_idx[e];
    int c0 = coords[vi * 3 + 0] - coords[vo * 3 + 0] + 1;
    int c1 = coords[vi * 3 + 1] - coords[vo * 3 + 1] + 1;
    int c2 = coords[vi * 3 + 2] - coords[vo * 3 + 2] + 1;
    int k1d = (c0 * 3 + c1) * 3 + c2;
    float4 f = in_feats4[vi * GROUPS + g];
    float4 w = kws[k1d * GROUPS + g];
    float* o = out + vo * NCH + g * 4;
    atomicAdd(o + 0, f.x * w.x);
    atomicAdd(o + 1, f.y * w.y);
    atomicAdd(o + 2, f.z * w.z);
    atomicAdd(o + 3, f.w * w.w);
}

extern "C" void kernel_launch(void* const* d_in, const int* in_sizes, int n_in,
                              void* d_out, int out_size, void* d_ws, size_t ws_size,
                              hipStream_t stream) {
    const int*   coords   = (const int*)d_in[0];
    const int*   in_idx   = (const int*)d_in[1];
    const int*   out_idx  = (const int*)d_in[2];
    const float* in_feats = (const float*)d_in[3];
    const float* kernel   = (const float*)d_in[4];

    const int E     = in_sizes[1];
    const int Nrows = out_size / NCH;

    const size_t dense_bytes = (size_t)LP * LP * LP * sizeof(int); // 4.25 MB

    if (ws_size >= dense_bytes) {
        int* dense = (int*)d_ws;
        // No memset: gather back-validates entries against coords.
        int block = 256;
        int grid1 = (Nrows + block - 1) / block;
        build_dense<<<grid1, block, 0, stream>>>(coords, dense, Nrows);

        gather_conv_region<<<NREGIONS, 256, 0, stream>>>(
            coords, dense, (const float4*)in_feats, (const float4*)kernel,
            (float4*)d_out, Nrows);
    } else {
        hipMemsetAsync(d_out, 0, (size_t)out_size * sizeof(float), stream);
        int total = E * GROUPS;
        int block = 256;
        int grid  = (total + block - 1) / block;
        mink_conv_scatter<<<grid, block, 0, stream>>>(
            coords, in_idx, out_idx,
            (const float4*)in_feats, (const float4*)kernel,
            (float*)d_out, E);
    }
}

// Round 4
// 135.789 us; speedup vs baseline: 1.0829x; 1.0829x over previous
//
#include <hip/hip_runtime.h>

#define NCH 32          // channels
#define GROUPS 8        // float4 groups per row (32 / 4)
#define KVOL 27         // 3^3 kernel offsets
#define LG 100          // grid side
#define LP 102          // padded side (1-cell zero ring)
#define RGN 5           // region side per block
#define NRGN 20         // LG / RGN
#define NREGIONS (NRGN * NRGN * NRGN)   // 8000
#define BSIDE 7         // RGN + 2
#define BVOL 343        // brick cells
#define CELLS 125       // RGN^3
#define LSTR 28         // uint taps per row (112B stride, 16B-aligned)

// ---- Kernel 1: padded dense presence map: dense[flatp] = row+1 --------------
__global__ void build_dense(const int* __restrict__ coords,
                            int* __restrict__ dense, int N) {
    int i = blockIdx.x * blockDim.x + threadIdx.x;
    if (i >= N) return;
    int x = coords[3 * i + 0];
    int y = coords[3 * i + 1];
    int z = coords[3 * i + 2];
    dense[((size_t)(x + 1) * LP + (y + 1)) * LP + (z + 1)] = i + 1;
}

// ---- Kernel 2: region gather ------------------------------------------------
// LDS 19.99KB -> 8 blocks/CU. kw rows at 128B stride: octet-g b128 reads
// cover banks 4g..4g+3 uniformly -> conflict-free. Tap entries are uint
// (row<<13 | k<<7): direct feat row + kw byte offset, no indirection.
// Ballot-based fill (no LDS atomics); rows count-sorted by tap count.
__global__ __launch_bounds__(256) void gather_conv_region(
        const int* __restrict__ dense,
        const float4* __restrict__ in_feats4,
        const float4* __restrict__ kernel4,
        float4* __restrict__ out4) {
    __shared__ float4 kw[(KVOL + 1) * GROUPS];      // 3584 B (row 27 = zeros)
    __shared__ int brick[BVOL];                     // row+1 (0 = empty) 1372 B
    __shared__ int qmeta[CELLS];                    // cell | nq<<9 | rank<<12
    __shared__ int smap[CELLS];                     // sorted -> (q<<4)|nq
    __shared__ int hist[7];
    __shared__ __align__(16) unsigned int list[CELLS * LSTR]; // 14000 B
    __shared__ int nint;

    int tid = threadIdx.x;
    int g   = tid & 7;

    if (tid == 0) nint = 0;
    if (tid < 7) hist[tid] = 0;
    if (tid < (KVOL + 1) * GROUPS) {
        int kr = tid >> 3;
        kw[tid] = (kr < KVOL) ? kernel4[tid]
                              : make_float4(0.f, 0.f, 0.f, 0.f);
    }

    // XCD slab swizzle (8000 % 8 == 0 -> bijective)
    int b = blockIdx.x;
    int r = (b & 7) * (NREGIONS >> 3) + (b >> 3);
    int bx = r / (NRGN * NRGN);
    int by = (r / NRGN) % NRGN;
    int bz = r % NRGN;
    int ox = bx * RGN, oy = by * RGN, oz = bz * RGN;

    // Brick load + interior queue (dense map is pre-zeroed; L2-hot, 4.25 MB).
    for (int i = tid; i < BVOL; i += 256) {
        int lx = i / 49, ly = (i / 7) % 7, lz = i % 7;
        int v = dense[((size_t)(ox + lx) * LP + (oy + ly)) * LP + (oz + lz)];
        brick[i] = v;
        if (v && (unsigned)(lx - 1) < RGN && (unsigned)(ly - 1) < RGN &&
            (unsigned)(lz - 1) < RGN) {
            int p = atomicAdd(&nint, 1);
            qmeta[p] = i;                            // cell in bits 0..8
        }
    }
    __syncthreads();

    int n = nint;

    // Fill: one octet per queued cell; lanes cover k = l, l+8, l+16, l+24.
    // Positions via ballot-prefix within the octet -> no atomics, dword writes.
    int oct = tid >> 3, l = tid & 7;
    int rounds = (n + 31) >> 5;                      // block-uniform
    for (int rd = 0; rd < rounds; ++rd) {
        int q = (rd << 5) + oct;
        bool valid = q < n;
        int cell = valid ? (qmeta[q] & 511) : 0;
        int cnt = 0;
        unsigned base = (unsigned)q * LSTR;
        #pragma unroll
        for (int s = 0; s < 4; ++s) {
            int k = l + (s << 3);
            int nb = 0;
            if (valid && k < KVOL) {
                int off = (k / 9) * 49 + ((k / 3) % 3) * 7 + (k % 3) - 57;
                nb = brick[cell + off];
            }
            unsigned long long bal = __ballot(nb > 0);
            int byte = (int)((bal >> ((oct & 7) << 3)) & 0xFF);
            if (nb > 0) {
                int pos = cnt + __popc(byte & ((1 << l) - 1));
                list[base + pos] =
                    ((unsigned)(nb - 1) << 13) | ((unsigned)k << 7);
            }
            cnt += __popc(byte);
        }
        if (valid && l == 0) {
            int j = cnt;                             // >=1 (center tap)
            unsigned dummy =
                ((unsigned)(brick[cell] - 1) << 13) | (27u << 7);
            while (j & 3) list[base + (j++)] = dummy; // k=27 row: zero weights
            int nq = j >> 2;                         // 1..7
            int h = atomicAdd(&hist[nq - 1], 1);
            qmeta[q] = cell | (nq << 9) | (h << 12);
        }
    }
    __syncthreads();

    // Placement: descending tap count -> octets in a wave get equal trips.
    if (tid < n) {
        int m  = qmeta[tid];
        int nq = (m >> 9) & 7;
        int pos = m >> 12;
        #pragma unroll
        for (int bb = 1; bb < 7; ++bb)
            if (bb >= nq) pos += hist[bb];
        smap[pos] = (tid << 4) | nq;
    }
    __syncthreads();

    // Gather: octet per row; 1 b128 list read + 4 global feat loads +
    // 4 conflict-free kw b128 reads + 16 FMA per 4 taps.
    const char* kwb = (const char*)kw + (g << 4);
    int lr = tid >> 3;
    for (int base = 0; base < n; base += 32) {
        int lo = base + lr;
        if (lo < n) {
            int d    = smap[lo];
            int q    = d >> 4;
            int nq   = d & 15;
            int orow = brick[qmeta[q] & 511] - 1;
            const uint4* tl = (const uint4*)&list[(unsigned)q * LSTR];
            float4 acc = make_float4(0.f, 0.f, 0.f, 0.f);
            for (int jq = 0; jq < nq; ++jq) {
                uint4 L = tl[jq];
                float4 f0 = in_feats4[(size_t)(L.x >> 13) * GROUPS + g];
                float4 f1 = in_feats4[(size_t)(L.y >> 13) * GROUPS + g];
                float4 f2 = in_feats4[(size_t)(L.z >> 13) * GROUPS + g];
                float4 f3 = in_feats4[(size_t)(L.w >> 13) * GROUPS + g];
                float4 w0 = *(const float4*)(kwb + (L.x & 0x1F80u));
                float4 w1 = *(const float4*)(kwb + (L.y & 0x1F80u));
                float4 w2 = *(const float4*)(kwb + (L.z & 0x1F80u));
                float4 w3 = *(const float4*)(kwb + (L.w & 0x1F80u));
                acc.x += f0.x * w0.x; acc.y += f0.y * w0.y;
                acc.z += f0.z * w0.z; acc.w += f0.w * w0.w;
                acc.x += f1.x * w1.x; acc.y += f1.y * w1.y;
                acc.z += f1.z * w1.z; acc.w += f1.w * w1.w;
                acc.x += f2.x * w2.x; acc.y += f2.y * w2.y;
                acc.z += f2.z * w2.z; acc.w += f2.w * w2.w;
                acc.x += f3.x * w3.x; acc.y += f3.y * w3.y;
                acc.z += f3.z * w3.z; acc.w += f3.w * w3.w;
            }
            out4[(size_t)orow * GROUPS + g] = acc;
        }
    }
}

// ---- Fallback (atomic scatter) if ws is too small ---------------------------
__global__ void mink_conv_scatter(const int* __restrict__ coords,
                                  const int* __restrict__ in_idx,
                                  const int* __restrict__ out_idx,
                                  const float4* __restrict__ in_feats4,
                                  const float4* __restrict__ kernel4,
                                  float* __restrict__ out,
                                  int E) {
    __shared__ float4 kws[KVOL * GROUPS];
    for (int i = threadIdx.x; i < KVOL * GROUPS; i += blockDim.x)
        kws[i] = kernel4[i];
    __syncthreads();
    int t = blockIdx.x * blockDim.x + threadIdx.x;
    if (t >= E * GROUPS) return;
    int e = t >> 3, g = t & 7;
    int vi = in_idx[e], vo = out_idx[e];
    int c0 = coords[vi * 3 + 0] - coords[vo * 3 + 0] + 1;
    int c1 = coords[vi * 3 + 1] - coords[vo * 3 + 1] + 1;
    int c2 = coords[vi * 3 + 2] - coords[vo * 3 + 2] + 1;
    int k1d = (c0 * 3 + c1) * 3 + c2;
    float4 f = in_feats4[vi * GROUPS + g];
    float4 w = kws[k1d * GROUPS + g];
    float* o = out + vo * NCH + g * 4;
    atomicAdd(o + 0, f.x * w.x);
    atomicAdd(o + 1, f.y * w.y);
    atomicAdd(o + 2, f.z * w.z);
    atomicAdd(o + 3, f.w * w.w);
}

extern "C" void kernel_launch(void* const* d_in, const int* in_sizes, int n_in,
                              void* d_out, int out_size, void* d_ws, size_t ws_size,
                              hipStream_t stream) {
    const int*   coords   = (const int*)d_in[0];
    const int*   in_idx   = (const int*)d_in[1];
    const int*   out_idx  = (const int*)d_in[2];
    const float* in_feats = (const float*)d_in[3];
    const float* kernel   = (const float*)d_in[4];

    const int E     = in_sizes[1];
    const int Nrows = out_size / NCH;

    const size_t dense_bytes = (size_t)LP * LP * LP * sizeof(int); // 4.25 MB

    if (ws_size >= dense_bytes) {
        int* dense = (int*)d_ws;
        hipMemsetAsync(dense, 0, dense_bytes, stream);

        int block = 256;
        int grid1 = (Nrows + block - 1) / block;
        build_dense<<<grid1, block, 0, stream>>>(coords, dense, Nrows);

        gather_conv_region<<<NREGIONS, 256, 0, stream>>>(
            dense, (const float4*)in_feats, (const float4*)kernel,
            (float4*)d_out);
    } else {
        hipMemsetAsync(d_out, 0, (size_t)out_size * sizeof(float), stream);
        int total = E * GROUPS;
        int block = 256;
        int grid  = (total + block - 1) / block;
        mink_conv_scatter<<<grid, block, 0, stream>>>(
            coords, in_idx, out_idx,
            (const float4*)in_feats, (const float4*)kernel,
            (float*)d_out, E);
    }
}